// Round 1
// baseline (975.359 us; speedup 1.0000x reference)
//
#include <hip/hip_runtime.h>

#define NUM_EMB 1024
#define EMB_DIM 256
#define ROWS 16
#define NTHREADS 256
#define NBLOCKS 2048              // 32768 rows / 16
#define TOTAL_ROWS 32768

__device__ __forceinline__ unsigned int sortable(float f) {
    unsigned int u = __float_as_uint(f);
    return (u & 0x80000000u) ? ~u : (u | 0x80000000u);
}

__device__ __forceinline__ unsigned long long umin64(unsigned long long a, unsigned long long b) {
    return a < b ? a : b;
}

// ---- prep: transpose E (256 x 1024) -> ET (1024 x 256), LDS-tiled ----
__global__ void vq_transpose(const float* __restrict__ E, float* __restrict__ ET) {
    __shared__ float tile[64][65];
    const int t = threadIdx.x;
    const int j0 = (blockIdx.x & 15) * 64;   // codebook-index tile
    const int d0 = (blockIdx.x >> 4) * 64;   // dim tile
    const int tj = t & 63, td = t >> 6;
#pragma unroll
    for (int k = 0; k < 16; k++) {
        int dl = k * 4 + td;
        tile[dl][tj] = E[(d0 + dl) * NUM_EMB + j0 + tj];
    }
    __syncthreads();
    const int dd = t & 63, tw = t >> 6;
#pragma unroll
    for (int k = 0; k < 16; k++) {
        int jj = k * 4 + tw;
        ET[(j0 + jj) * EMB_DIM + d0 + dd] = tile[dd][jj];
    }
}

// ---- prep: normE[j] = sum_d E[d][j]^2  (coalesced across threads) ----
__global__ void vq_norms(const float* __restrict__ E, float* __restrict__ normE) {
    const int j = blockIdx.x * blockDim.x + threadIdx.x;
    float s = 0.f;
#pragma unroll 8
    for (int d = 0; d < EMB_DIM; d++) {
        float v = E[d * NUM_EMB + j];
        s = fmaf(v, v, s);
    }
    normE[j] = s;
}

// ---- main: distances + argmin + gather + straight-through out + loss partials ----
__global__ __launch_bounds__(NTHREADS, 4)
void vq_main(const float* __restrict__ X, const float* __restrict__ E,
             const float* __restrict__ ET, const float* __restrict__ normE,
             float* __restrict__ out, float* __restrict__ partial) {
    __shared__ __align__(16) float xs[ROWS][EMB_DIM];   // 16 KB
    __shared__ float r2part[ROWS][16];
    __shared__ float r2s[ROWS];
    __shared__ unsigned long long wkey[ROWS][4];
    __shared__ int idxs[ROWS];
    __shared__ float lred[4];

    const int t = threadIdx.x;
    const long long base = (long long)blockIdx.x * (ROWS * EMB_DIM);

    // stage X rows to LDS (coalesced float4)
    {
        const float4* Xv = (const float4*)(X + base);
        float4* xsv = (float4*)(&xs[0][0]);
#pragma unroll
        for (int i = 0; i < 4; i++)
            xsv[i * NTHREADS + t] = Xv[i * NTHREADS + t];
    }
    __syncthreads();

    // per-row ||x||^2 (16 partials of 16, then combine)
    {
        const int r = t >> 4, l = t & 15;
        float s = 0.f;
#pragma unroll
        for (int k = 0; k < 16; k++) {
            float v = xs[r][l * 16 + k];
            s = fmaf(v, v, s);
        }
        r2part[r][l] = s;
    }
    __syncthreads();
    if (t < ROWS) {
        float s = 0.f;
#pragma unroll
        for (int k = 0; k < 16; k++) s += r2part[t][k];
        r2s[t] = s;
    }
    __syncthreads();

    // dot products: thread t owns codebook columns c0..c0+3
    const int c0 = t * 4;
    float4 acc[ROWS];
#pragma unroll
    for (int r = 0; r < ROWS; r++) acc[r] = make_float4(0.f, 0.f, 0.f, 0.f);

    const float* Eb = E + c0;
    for (int d = 0; d < EMB_DIM; d += 4) {
        const float4 e0 = *(const float4*)(Eb + (d + 0) * NUM_EMB);
        const float4 e1 = *(const float4*)(Eb + (d + 1) * NUM_EMB);
        const float4 e2 = *(const float4*)(Eb + (d + 2) * NUM_EMB);
        const float4 e3 = *(const float4*)(Eb + (d + 3) * NUM_EMB);
#pragma unroll
        for (int r = 0; r < ROWS; r++) {
            const float4 xv = *(const float4*)(&xs[r][d]);  // wave-uniform broadcast
            acc[r].x = fmaf(xv.x, e0.x, acc[r].x);
            acc[r].y = fmaf(xv.x, e0.y, acc[r].y);
            acc[r].z = fmaf(xv.x, e0.z, acc[r].z);
            acc[r].w = fmaf(xv.x, e0.w, acc[r].w);
            acc[r].x = fmaf(xv.y, e1.x, acc[r].x);
            acc[r].y = fmaf(xv.y, e1.y, acc[r].y);
            acc[r].z = fmaf(xv.y, e1.z, acc[r].z);
            acc[r].w = fmaf(xv.y, e1.w, acc[r].w);
            acc[r].x = fmaf(xv.z, e2.x, acc[r].x);
            acc[r].y = fmaf(xv.z, e2.y, acc[r].y);
            acc[r].z = fmaf(xv.z, e2.z, acc[r].z);
            acc[r].w = fmaf(xv.z, e2.w, acc[r].w);
            acc[r].x = fmaf(xv.w, e3.x, acc[r].x);
            acc[r].y = fmaf(xv.w, e3.y, acc[r].y);
            acc[r].z = fmaf(xv.w, e3.z, acc[r].z);
            acc[r].w = fmaf(xv.w, e3.w, acc[r].w);
        }
    }

    // dist = (r2 + normE) - 2*dot  (reference op order), pack+argmin
    const float4 ne = *(const float4*)(normE + c0);
#pragma unroll
    for (int r = 0; r < ROWS; r++) {
        const float r2 = r2s[r];
        const float f0 = (r2 + ne.x) - 2.0f * acc[r].x;
        const float f1 = (r2 + ne.y) - 2.0f * acc[r].y;
        const float f2 = (r2 + ne.z) - 2.0f * acc[r].z;
        const float f3 = (r2 + ne.w) - 2.0f * acc[r].w;
        unsigned long long k0 = ((unsigned long long)sortable(f0) << 32) | (unsigned)(c0 + 0);
        unsigned long long k1 = ((unsigned long long)sortable(f1) << 32) | (unsigned)(c0 + 1);
        unsigned long long k2 = ((unsigned long long)sortable(f2) << 32) | (unsigned)(c0 + 2);
        unsigned long long k3 = ((unsigned long long)sortable(f3) << 32) | (unsigned)(c0 + 3);
        unsigned long long km = umin64(umin64(k0, k1), umin64(k2, k3));
#pragma unroll
        for (int off = 32; off; off >>= 1) {
            unsigned long long o = __shfl_xor(km, off, 64);
            km = umin64(km, o);
        }
        if ((t & 63) == 0) wkey[r][t >> 6] = km;
    }
    __syncthreads();
    if (t < ROWS) {
        unsigned long long m = umin64(umin64(wkey[t][0], wkey[t][1]),
                                      umin64(wkey[t][2], wkey[t][3]));
        idxs[t] = (int)(m & 0xFFFFFFFFull);
    }
    __syncthreads();

    // gather codebook rows (coalesced from ET), straight-through out, loss partial
    float lsum = 0.f;
#pragma unroll
    for (int r = 0; r < ROWS; r++) {
        const int idx = idxs[r];
        const float q = ET[idx * EMB_DIM + t];
        const float x = xs[r][t];
        out[base + r * EMB_DIM + t] = x + (q - x);   // match ref rounding
        const float df = x - q;
        lsum = fmaf(df, df, lsum);
    }
#pragma unroll
    for (int off = 32; off; off >>= 1) lsum += __shfl_down(lsum, off, 64);
    if ((t & 63) == 0) lred[t >> 6] = lsum;
    __syncthreads();
    if (t == 0) partial[blockIdx.x] = (lred[0] + lred[1]) + (lred[2] + lred[3]);
}

// ---- finish: deterministic partial-sum reduce, loss = m + 0.25*m ----
__global__ void vq_finish(const float* __restrict__ partial, float* __restrict__ loss_out) {
    __shared__ float red[256];
    const int t = threadIdx.x;
    float s = 0.f;
    for (int i = t; i < NBLOCKS; i += 256) s += partial[i];
    red[t] = s;
    __syncthreads();
    for (int k = 128; k > 0; k >>= 1) {
        if (t < k) red[t] += red[t + k];
        __syncthreads();
    }
    if (t == 0) {
        const float m = red[0] / 8388608.0f;   // exact: /2^23
        loss_out[0] = fmaf(0.25f, m, m);       // emb_loss + BETA*commitment
    }
}

extern "C" void kernel_launch(void* const* d_in, const int* in_sizes, int n_in,
                              void* d_out, int out_size, void* d_ws, size_t ws_size,
                              hipStream_t stream) {
    const float* X = (const float*)d_in[0];      // (32,32,32,256) fp32
    const float* E = (const float*)d_in[1];      // (256,1024) fp32
    float* out = (float*)d_out;                  // 8388608 + 1 floats

    float* ET     = (float*)d_ws;                // 1024*256 floats
    float* normE  = ET + NUM_EMB * EMB_DIM;      // 1024 floats
    float* part   = normE + NUM_EMB;             // 2048 floats

    vq_transpose<<<64, 256, 0, stream>>>(E, ET);
    vq_norms<<<NUM_EMB / 256, 256, 0, stream>>>(E, normE);
    vq_main<<<NBLOCKS, NTHREADS, 0, stream>>>(X, E, ET, normE, out, part);
    vq_finish<<<1, 256, 0, stream>>>(part, out + (out_size - 1));
}

// Round 2
// 272.094 us; speedup vs baseline: 3.5846x; 3.5846x over previous
//
#include <hip/hip_runtime.h>

#define NUM_EMB 1024
#define EMB_DIM 256
#define ROWS 16
#define NT 512
#define NBLOCKS 2048              // 32768 rows / 16
#define NWAVES (NT / 64)

__device__ __forceinline__ unsigned int sortable(float f) {
    unsigned int u = __float_as_uint(f);
    return (u & 0x80000000u) ? ~u : (u | 0x80000000u);
}

__device__ __forceinline__ unsigned long long umin64(unsigned long long a, unsigned long long b) {
    return a < b ? a : b;
}

// ---- prep: transpose E (256 x 1024) -> ET (1024 x 256), LDS-tiled ----
__global__ void vq_transpose(const float* __restrict__ E, float* __restrict__ ET) {
    __shared__ float tile[64][65];
    const int t = threadIdx.x;
    const int j0 = (blockIdx.x & 15) * 64;   // codebook-index tile
    const int d0 = (blockIdx.x >> 4) * 64;   // dim tile
    const int tj = t & 63, td = t >> 6;
#pragma unroll
    for (int k = 0; k < 16; k++) {
        int dl = k * 4 + td;
        tile[dl][tj] = E[(d0 + dl) * NUM_EMB + j0 + tj];
    }
    __syncthreads();
    const int dd = t & 63, tw = t >> 6;
#pragma unroll
    for (int k = 0; k < 16; k++) {
        int jj = k * 4 + tw;
        ET[(j0 + jj) * EMB_DIM + d0 + dd] = tile[dd][jj];
    }
}

// ---- prep: normE[j] = sum_d E[d][j]^2  (coalesced across threads) ----
__global__ void vq_norms(const float* __restrict__ E, float* __restrict__ normE) {
    const int j = blockIdx.x * blockDim.x + threadIdx.x;
    float s = 0.f;
#pragma unroll 8
    for (int d = 0; d < EMB_DIM; d++) {
        float v = E[d * NUM_EMB + j];
        s = fmaf(v, v, s);
    }
    normE[j] = s;
}

// ---- main: distances + argmin + gather + straight-through out + loss partials ----
// 512 threads, 2 codebook cols per thread -> 32 float accumulators (no spill).
__global__ __launch_bounds__(NT)
void vq_main(const float* __restrict__ X, const float* __restrict__ E,
             const float* __restrict__ ET, const float* __restrict__ normE,
             float* __restrict__ out, float* __restrict__ partial) {
    __shared__ __align__(16) float xs[ROWS][EMB_DIM];   // 16 KB
    __shared__ float r2part[ROWS][32];
    __shared__ float r2s[ROWS];
    __shared__ unsigned long long wkey[ROWS][NWAVES];
    __shared__ int idxs[ROWS];
    __shared__ float lred[NWAVES];

    const int t = threadIdx.x;
    const long long base = (long long)blockIdx.x * (ROWS * EMB_DIM);

    // stage X rows to LDS (coalesced float4)
    {
        const float4* Xv = (const float4*)(X + base);
        float4* xsv = (float4*)(&xs[0][0]);
        xsv[t] = Xv[t];
        xsv[t + NT] = Xv[t + NT];
    }
    __syncthreads();

    // per-row ||x||^2 (32 partials of 8, then combine)
    {
        const int r = t >> 5, l = t & 31;
        float s = 0.f;
#pragma unroll
        for (int k = 0; k < 8; k++) {
            float v = xs[r][l * 8 + k];
            s = fmaf(v, v, s);
        }
        r2part[r][l] = s;
    }
    __syncthreads();
    if (t < ROWS) {
        float s = 0.f;
#pragma unroll
        for (int k = 0; k < 32; k++) s += r2part[t][k];
        r2s[t] = s;
    }
    __syncthreads();

    // dot products: thread t owns codebook columns c0, c0+1
    const int c0 = t * 2;
    float2 acc[ROWS];
#pragma unroll
    for (int r = 0; r < ROWS; r++) acc[r] = make_float2(0.f, 0.f);

    const float* Eb = E + c0;
    for (int d = 0; d < EMB_DIM; d += 4) {
        const float2 e0 = *(const float2*)(Eb + (d + 0) * NUM_EMB);
        const float2 e1 = *(const float2*)(Eb + (d + 1) * NUM_EMB);
        const float2 e2 = *(const float2*)(Eb + (d + 2) * NUM_EMB);
        const float2 e3 = *(const float2*)(Eb + (d + 3) * NUM_EMB);
#pragma unroll
        for (int r = 0; r < ROWS; r++) {
            const float4 xv = *(const float4*)(&xs[r][d]);  // wave-uniform broadcast
            acc[r].x = fmaf(xv.x, e0.x, acc[r].x);
            acc[r].y = fmaf(xv.x, e0.y, acc[r].y);
            acc[r].x = fmaf(xv.y, e1.x, acc[r].x);
            acc[r].y = fmaf(xv.y, e1.y, acc[r].y);
            acc[r].x = fmaf(xv.z, e2.x, acc[r].x);
            acc[r].y = fmaf(xv.z, e2.y, acc[r].y);
            acc[r].x = fmaf(xv.w, e3.x, acc[r].x);
            acc[r].y = fmaf(xv.w, e3.y, acc[r].y);
        }
    }

    // dist = (r2 + normE) - 2*dot  (reference op order), pack+argmin
    const float2 ne = *(const float2*)(normE + c0);
#pragma unroll
    for (int r = 0; r < ROWS; r++) {
        const float r2 = r2s[r];
        const float f0 = (r2 + ne.x) - 2.0f * acc[r].x;
        const float f1 = (r2 + ne.y) - 2.0f * acc[r].y;
        unsigned long long k0 = ((unsigned long long)sortable(f0) << 32) | (unsigned)(c0 + 0);
        unsigned long long k1 = ((unsigned long long)sortable(f1) << 32) | (unsigned)(c0 + 1);
        unsigned long long km = umin64(k0, k1);
#pragma unroll
        for (int off = 32; off; off >>= 1) {
            unsigned long long o = __shfl_xor(km, off, 64);
            km = umin64(km, o);
        }
        if ((t & 63) == 0) wkey[r][t >> 6] = km;
    }
    __syncthreads();
    if (t < ROWS) {
        unsigned long long m = wkey[t][0];
#pragma unroll
        for (int w = 1; w < NWAVES; w++) m = umin64(m, wkey[t][w]);
        idxs[t] = (int)(m & 0xFFFFFFFFull);
    }
    __syncthreads();

    // gather codebook rows (coalesced from ET), straight-through out, loss partial
    // 512 threads: two halves of 256 lanes each handle 8 rows apiece
    const int dcol = t & 255;
    const int half = t >> 8;
    float lsum = 0.f;
#pragma unroll
    for (int rr = 0; rr < 8; rr++) {
        const int r = half * 8 + rr;
        const int idx = idxs[r];
        const float q = ET[idx * EMB_DIM + dcol];
        const float x = xs[r][dcol];
        out[base + r * EMB_DIM + dcol] = x + (q - x);   // match ref rounding
        const float df = x - q;
        lsum = fmaf(df, df, lsum);
    }
#pragma unroll
    for (int off = 32; off; off >>= 1) lsum += __shfl_down(lsum, off, 64);
    if ((t & 63) == 0) lred[t >> 6] = lsum;
    __syncthreads();
    if (t == 0) {
        float s = 0.f;
#pragma unroll
        for (int w = 0; w < NWAVES; w++) s += lred[w];
        partial[blockIdx.x] = s;
    }
}

// ---- finish: deterministic partial-sum reduce, loss = m + 0.25*m ----
__global__ void vq_finish(const float* __restrict__ partial, float* __restrict__ loss_out) {
    __shared__ float red[256];
    const int t = threadIdx.x;
    float s = 0.f;
    for (int i = t; i < NBLOCKS; i += 256) s += partial[i];
    red[t] = s;
    __syncthreads();
    for (int k = 128; k > 0; k >>= 1) {
        if (t < k) red[t] += red[t + k];
        __syncthreads();
    }
    if (t == 0) {
        const float m = red[0] / 8388608.0f;   // exact: /2^23
        loss_out[0] = fmaf(0.25f, m, m);       // emb_loss + BETA*commitment
    }
}

extern "C" void kernel_launch(void* const* d_in, const int* in_sizes, int n_in,
                              void* d_out, int out_size, void* d_ws, size_t ws_size,
                              hipStream_t stream) {
    const float* X = (const float*)d_in[0];      // (32,32,32,256) fp32
    const float* E = (const float*)d_in[1];      // (256,1024) fp32
    float* out = (float*)d_out;                  // 8388608 + 1 floats

    float* ET     = (float*)d_ws;                // 1024*256 floats
    float* normE  = ET + NUM_EMB * EMB_DIM;      // 1024 floats
    float* part   = normE + NUM_EMB;             // 2048 floats

    vq_transpose<<<64, 256, 0, stream>>>(E, ET);
    vq_norms<<<NUM_EMB / 256, 256, 0, stream>>>(E, normE);
    vq_main<<<NBLOCKS, NT, 0, stream>>>(X, E, ET, normE, out, part);
    vq_finish<<<1, 256, 0, stream>>>(part, out + (out_size - 1));
}

// Round 4
// 155.773 us; speedup vs baseline: 6.2614x; 1.7467x over previous
//
#include <hip/hip_runtime.h>

#define NUM_EMB 1024
#define EMB_DIM 256
#define MARGIN 1e-3f

typedef __attribute__((ext_vector_type(8))) short short8v;
typedef __attribute__((ext_vector_type(4))) float f32x4;
typedef unsigned long long u64;
typedef unsigned int u32;

__device__ __forceinline__ u32 sortable(float f) {
    u32 u = __float_as_uint(f);
    return (u & 0x80000000u) ? ~u : (u | 0x80000000u);
}
__device__ __forceinline__ float unsortable(u32 s) {
    u32 u = (s & 0x80000000u) ? (s & 0x7FFFFFFFu) : ~s;
    return __uint_as_float(u);
}
__device__ __forceinline__ u64 umin64(u64 a, u64 b) { return a < b ? a : b; }

// RNE fp32 -> bf16 bits
__device__ __forceinline__ unsigned short f2bf(float f) {
    u32 u = __float_as_uint(f);
    u32 r = (u + 0x7FFFu + ((u >> 16) & 1u)) >> 16;
    return (unsigned short)r;
}
__device__ __forceinline__ float bf2f(unsigned short h) {
    return __uint_as_float(((u32)h) << 16);
}

#define GLP(p)  ((const __attribute__((address_space(1))) unsigned int*)(p))
#define LDSP(p) ((__attribute__((address_space(3))) unsigned int*)(p))

// ---- prep: transpose E (256 x 1024) -> ET (1024 x 256) ----
__global__ void vq_transpose(const float* __restrict__ E, float* __restrict__ ET) {
    __shared__ float tile[64][65];
    const int t = threadIdx.x;
    const int j0 = (blockIdx.x & 15) * 64;
    const int d0 = (blockIdx.x >> 4) * 64;
    const int tj = t & 63, td = t >> 6;
#pragma unroll
    for (int k = 0; k < 16; k++) {
        int dl = k * 4 + td;
        tile[dl][tj] = E[(d0 + dl) * NUM_EMB + j0 + tj];
    }
    __syncthreads();
    const int dd = t & 63, tw = t >> 6;
#pragma unroll
    for (int k = 0; k < 16; k++) {
        int jj = k * 4 + tw;
        ET[(j0 + jj) * EMB_DIM + d0 + dd] = tile[dd][jj];
    }
}

// ---- prep: normE[j] = sum_d E[d][j]^2 ----
__global__ void vq_norms(const float* __restrict__ E, float* __restrict__ normE) {
    const int j = blockIdx.x * blockDim.x + threadIdx.x;
    float s = 0.f;
#pragma unroll 8
    for (int d = 0; d < EMB_DIM; d++) {
        float v = E[d * NUM_EMB + j];
        s = fmaf(v, v, s);
    }
    normE[j] = s;
}

// ---- prep: X -> Xs bf16 hi/lo, tiled+swizzled [mblk 256][kstep 8][16KB tile] ----
// ksteps 0..3 = hi(d 0..255), 4..7 = lo(d 0..255)
// tile byte = (row_local*128 + klocal*2) ^ ((row_local&7)<<4)
__global__ __launch_bounds__(512) void vq_xprep(const float* __restrict__ X, char* __restrict__ Xs) {
    const int mblk = blockIdx.x;            // 0..255
    const int t = threadIdx.x;
#pragma unroll
    for (int i = 0; i < 8; i++) {
        int gid = i * 512 + t;              // 0..4095 = 128 rows x 32 d8-groups
        int row = gid >> 5;                 // 0..127
        int d0 = (gid & 31) * 8;            // 0..248
        const float* xp = X + ((size_t)mblk * 128 + row) * 256 + d0;
        short8v vh, vl;
#pragma unroll
        for (int j = 0; j < 8; j++) {
            float x = xp[j];
            unsigned short h = f2bf(x);
            float hf = bf2f(h);
            unsigned short lo = f2bf(x - hf);
            vh[j] = (short)h;
            vl[j] = (short)lo;
        }
        int ksh = d0 >> 6, kl = d0 & 63;
        size_t inner = (size_t)(((row * 128 + kl * 2) ^ ((row & 7) << 4)));
        size_t base = (size_t)mblk * 131072;
        *(short8v*)(Xs + base + (size_t)ksh * 16384 + inner) = vh;
        *(short8v*)(Xs + base + (size_t)(ksh + 4) * 16384 + inner) = vl;
    }
}

// ---- prep: E -> Es bf16 hi/lo, tiled+swizzled [nblk 4][ks 8][32KB tile] ----
// ks 0..3 = eh(d 0..255), ks 4..7 = el(d 0..255)
// tile byte = (col_local*128 + klocal*2) ^ ((col_local&7)<<4)
__global__ __launch_bounds__(512) void vq_eprep(const float* __restrict__ E, char* __restrict__ Es) {
    const int bid = blockIdx.x;             // 0..31
    const int nblk = bid >> 3, ks = bid & 7;
    const int t = threadIdx.x;
#pragma unroll
    for (int i = 0; i < 4; i++) {
        int gid = i * 512 + t;              // 0..2047 = 256 cols x 8 k8-groups
        int col = gid >> 3;                 // 0..255
        int k8 = gid & 7;                   // 0..7
        int kg = ks * 64 + k8 * 8;          // k within [0,512)
        int isLo = kg >= 256;
        int d0 = isLo ? kg - 256 : kg;
        int colg = nblk * 256 + col;
        short8v v;
#pragma unroll
        for (int j = 0; j < 8; j++) {
            float e = E[(d0 + j) * NUM_EMB + colg];
            unsigned short h = f2bf(e);
            if (isLo) h = f2bf(e - bf2f(h));
            v[j] = (short)h;
        }
        size_t off = (size_t)nblk * 262144 + (size_t)ks * 32768 +
                     (size_t)(((col * 128 + (k8 * 8) * 2) ^ ((col & 7) << 4)));
        *(short8v*)(Es + off) = v;
    }
}

// ---- GEMM + per-block argmin/second-best ----
// grid 1024 = 256 mblk x 4 nblk; 512 thr; BM=128 BN=256 BK=64; dbuf LDS 96KB
// K=768 schedule: D = Xh*Eh + Xh*El + Xl*Eh
//   s 0..3 : A kstep s   (xh), B ks s   (eh)
//   s 4..7 : A kstep s-4 (xh), B ks s   (el)
//   s 8..11: A kstep s-4 (xl), B ks s-8 (eh)
__global__ __launch_bounds__(512, 1)
void vq_gemm(const char* __restrict__ Xs, const char* __restrict__ Es,
             const float* __restrict__ normE,
             u64* __restrict__ gkey, float* __restrict__ gm2) {
    extern __shared__ char smem[];
    const int t = threadIdx.x;
    const int bid = blockIdx.x;
    const int mblk = bid >> 2;
    const int nblk = bid & 3;
    const int w = t >> 6, l = t & 63;
    const int wm = w >> 2, wn = w & 3;
    const int lr = l & 15, lg = l >> 4;
    const int swz = (l & 7) << 4;

    const char* Asrc = Xs + (size_t)mblk * 131072;
    const char* Bsrc = Es + (size_t)nblk * 262144;

    // LDS frag bases (per lane), buf-relative
    const int aB0 = (wm * 64 + lr) * 128 + ((lg * 16) ^ swz);
    const int aB1 = (wm * 64 + lr) * 128 + ((64 + lg * 16) ^ swz);
    const int bB0 = 16384 + (wn * 64 + lr) * 128 + ((lg * 16) ^ swz);
    const int bB1 = 16384 + (wn * 64 + lr) * 128 + ((64 + lg * 16) ^ swz);

    f32x4 acc[4][4];
#pragma unroll
    for (int mt = 0; mt < 4; mt++)
#pragma unroll
        for (int nt = 0; nt < 4; nt++) acc[mt][nt] = (f32x4){0.f, 0.f, 0.f, 0.f};

#define STAGE(aks, bks, buf) {                                                    \
    const char* as_ = Asrc + (aks) * 16384;                                       \
    const char* bs_ = Bsrc + (bks) * 32768;                                       \
    char* ab_ = smem + (buf) * 49152;                                             \
    char* bb_ = ab_ + 16384;                                                      \
    __builtin_amdgcn_global_load_lds(GLP(as_ + t * 16),        LDSP(ab_ + t * 16), 16, 0, 0);        \
    __builtin_amdgcn_global_load_lds(GLP(as_ + 8192 + t * 16), LDSP(ab_ + 8192 + t * 16), 16, 0, 0); \
    __builtin_amdgcn_global_load_lds(GLP(bs_ + t * 16),         LDSP(bb_ + t * 16), 16, 0, 0);        \
    __builtin_amdgcn_global_load_lds(GLP(bs_ + 8192 + t * 16),  LDSP(bb_ + 8192 + t * 16), 16, 0, 0); \
    __builtin_amdgcn_global_load_lds(GLP(bs_ + 16384 + t * 16), LDSP(bb_ + 16384 + t * 16), 16, 0, 0);\
    __builtin_amdgcn_global_load_lds(GLP(bs_ + 24576 + t * 16), LDSP(bb_ + 24576 + t * 16), 16, 0, 0);\
}

    STAGE(0, 0, 0);
#pragma unroll
    for (int s = 0; s < 12; s++) {
        if (s < 11) {
            const int s1 = s + 1;
            const int an = (s1 < 8) ? (s1 & 3) : (s1 - 4);
            const int bn = (s1 < 8) ? s1 : (s1 - 8);
            STAGE(an, bn, s1 & 1);
            asm volatile("s_waitcnt vmcnt(6)" ::: "memory");
        } else {
            asm volatile("s_waitcnt vmcnt(0)" ::: "memory");
        }
        __builtin_amdgcn_s_barrier();
        asm volatile("" ::: "memory");
        {
            const char* s0 = smem + (s & 1) * 49152;
            short8v a0[4], b0[4];
#pragma unroll
            for (int mt = 0; mt < 4; mt++) a0[mt] = *(const short8v*)(s0 + aB0 + mt * 2048);
#pragma unroll
            for (int nt = 0; nt < 4; nt++) b0[nt] = *(const short8v*)(s0 + bB0 + nt * 2048);
#pragma unroll
            for (int mt = 0; mt < 4; mt++)
#pragma unroll
                for (int nt = 0; nt < 4; nt++)
                    acc[mt][nt] = __builtin_amdgcn_mfma_f32_16x16x32_bf16(a0[mt], b0[nt], acc[mt][nt], 0, 0, 0);
            short8v a1[4], b1[4];
#pragma unroll
            for (int mt = 0; mt < 4; mt++) a1[mt] = *(const short8v*)(s0 + aB1 + mt * 2048);
#pragma unroll
            for (int nt = 0; nt < 4; nt++) b1[nt] = *(const short8v*)(s0 + bB1 + nt * 2048);
#pragma unroll
            for (int mt = 0; mt < 4; mt++)
#pragma unroll
                for (int nt = 0; nt < 4; nt++)
                    acc[mt][nt] = __builtin_amdgcn_mfma_f32_16x16x32_bf16(a1[mt], b1[nt], acc[mt][nt], 0, 0, 0);
        }
        asm volatile("" ::: "memory");
        __builtin_amdgcn_s_barrier();
    }
#undef STAGE

    // epilogue: per-lane argmin over nt, then 16-lane reduce; track second-best
    float ne_v[4];
#pragma unroll
    for (int nt = 0; nt < 4; nt++) ne_v[nt] = normE[nblk * 256 + wn * 64 + nt * 16 + lr];

#pragma unroll
    for (int mt = 0; mt < 4; mt++) {
#pragma unroll
        for (int r = 0; r < 4; r++) {
            float m1 = __uint_as_float(0x7F7FFFFFu);   // FLT_MAX
            float m2 = m1;
            u32 col = 0;
#pragma unroll
            for (int nt = 0; nt < 4; nt++) {
                float f = fmaf(-2.0f, acc[mt][nt][r], ne_v[nt]);
                float mx = fmaxf(m1, f);
                m2 = fminf(m2, mx);
                bool p = f < m1;
                m1 = fminf(m1, f);
                u32 cg = (u32)(nblk * 256 + wn * 64 + nt * 16 + lr);
                col = p ? cg : col;
            }
            u64 key = ((u64)sortable(m1) << 32) | col;
#pragma unroll
            for (int off = 1; off < 16; off <<= 1) {
                u64 ko = __shfl_xor(key, off, 16);
                float m1o = __shfl_xor(m1, off, 16);
                float m2o = __shfl_xor(m2, off, 16);
                m2 = fminf(fminf(m2, m2o), fmaxf(m1, m1o));
                m1 = fminf(m1, m1o);
                key = umin64(key, ko);
            }
            if (lr == 0) {
                int slot = (wm * 64 + mt * 16 + lg * 4 + r) * 4 + wn;
                *(u64*)(smem + slot * 16) = key;
                *(float*)(smem + slot * 16 + 8) = m2;
            }
        }
    }
    __syncthreads();
    if (t < 128) {
        u64 k_i[4]; float m2_i[4];
#pragma unroll
        for (int i = 0; i < 4; i++) {
            k_i[i] = *(const u64*)(smem + (t * 4 + i) * 16);
            m2_i[i] = *(const float*)(smem + (t * 4 + i) * 16 + 8);
        }
        u64 K = umin64(umin64(k_i[0], k_i[1]), umin64(k_i[2], k_i[3]));
        float F2 = __uint_as_float(0x7F7FFFFFu);
#pragma unroll
        for (int i = 0; i < 4; i++) {
            float f1i = unsortable((u32)(k_i[i] >> 32));
            F2 = fminf(F2, (k_i[i] == K) ? m2_i[i] : f1i);
        }
        int rowg = mblk * 128 + t;
        gkey[(size_t)nblk * 32768 + rowg] = K;
        gm2[(size_t)nblk * 32768 + rowg] = F2;
    }
}

// ---- combine 4 nblk results -> idx + flag list ----
__global__ __launch_bounds__(512) void vq_combine(const u64* __restrict__ gkey, const float* __restrict__ gm2,
                                                  u32* __restrict__ idx_arr, u32* __restrict__ flaglist,
                                                  u32* __restrict__ cnt) {
    const int row = blockIdx.x * 512 + threadIdx.x;
    u64 k_i[4]; float m2_i[4];
#pragma unroll
    for (int n = 0; n < 4; n++) {
        k_i[n] = gkey[(size_t)n * 32768 + row];
        m2_i[n] = gm2[(size_t)n * 32768 + row];
    }
    u64 K = umin64(umin64(k_i[0], k_i[1]), umin64(k_i[2], k_i[3]));
    float F1 = unsortable((u32)(K >> 32));
    float F2 = __uint_as_float(0x7F7FFFFFu);
#pragma unroll
    for (int n = 0; n < 4; n++) {
        float f1i = unsortable((u32)(k_i[n] >> 32));
        F2 = fminf(F2, (k_i[n] == K) ? m2_i[n] : f1i);
    }
    idx_arr[row] = (u32)(K & 0xFFFFFFFFu);
    if (F2 - F1 < MARGIN) {
        u32 p = atomicAdd(cnt, 1u);
        flaglist[p] = (u32)row;
    }
}

// ---- exact fp32 recheck of flagged rows (bit-identical to verified round-2 math) ----
__global__ __launch_bounds__(512) void vq_recheck(const float* __restrict__ X, const float* __restrict__ E,
                                                  const float* __restrict__ normE,
                                                  const u32* __restrict__ flaglist, const u32* __restrict__ cnt,
                                                  u32* __restrict__ idx_arr) {
    __shared__ float xrow[256];
    __shared__ float r2part[32];
    __shared__ float r2s;
    __shared__ u64 wkey[8];
    const int t = threadIdx.x;
    const int n = (int)*cnt;
    for (int i = blockIdx.x; i < n; i += 256) {
        const int row = (int)flaglist[i];
        __syncthreads();
        if (t < 64) ((float4*)xrow)[t] = ((const float4*)(X + (size_t)row * 256))[t];
        __syncthreads();
        if (t < 32) {
            float s = 0.f;
#pragma unroll
            for (int k = 0; k < 8; k++) {
                float v = xrow[t * 8 + k];
                s = fmaf(v, v, s);
            }
            r2part[t] = s;
        }
        __syncthreads();
        if (t == 0) {
            float s = 0.f;
#pragma unroll
            for (int k = 0; k < 32; k++) s += r2part[k];
            r2s = s;
        }
        __syncthreads();
        const float r2 = r2s;
        const int c0 = t * 2;
        float ax = 0.f, ay = 0.f;
        for (int d = 0; d < 256; d += 4) {
#pragma unroll
            for (int dd = 0; dd < 4; dd++) {
                float xv = xrow[d + dd];
                float2 e = *(const float2*)(E + (d + dd) * NUM_EMB + c0);
                ax = fmaf(xv, e.x, ax);
                ay = fmaf(xv, e.y, ay);
            }
        }
        float2 ne = *(const float2*)(normE + c0);
        float f0 = (r2 + ne.x) - 2.0f * ax;
        float f1 = (r2 + ne.y) - 2.0f * ay;
        u64 k0 = ((u64)sortable(f0) << 32) | (u32)c0;
        u64 k1 = ((u64)sortable(f1) << 32) | (u32)(c0 + 1);
        u64 km = umin64(k0, k1);
#pragma unroll
        for (int off = 32; off; off >>= 1) km = umin64(km, __shfl_xor(km, off, 64));
        if ((t & 63) == 0) wkey[t >> 6] = km;
        __syncthreads();
        if (t == 0) {
            u64 m = wkey[0];
#pragma unroll
            for (int w2 = 1; w2 < 8; w2++) m = umin64(m, wkey[w2]);
            idx_arr[row] = (u32)(m & 0xFFFFFFFFull);
        }
    }
}

// ---- straight-through out + loss partials ----
__global__ __launch_bounds__(512) void vq_out(const float* __restrict__ X, const float* __restrict__ ET,
                                              const u32* __restrict__ idx_arr,
                                              float* __restrict__ out, float* __restrict__ partial) {
    __shared__ float lred[8];
    const int t = threadIdx.x;
    const long long base = (long long)blockIdx.x * 4096;   // 16 rows * 256
    const int dcol = t & 255, half = t >> 8;
    float lsum = 0.f;
#pragma unroll
    for (int rr = 0; rr < 8; rr++) {
        const int r = half * 8 + rr;
        const int row = blockIdx.x * 16 + r;
        const u32 idx = idx_arr[row];
        const float q = ET[(size_t)idx * EMB_DIM + dcol];
        const float x = X[base + r * EMB_DIM + dcol];
        out[base + r * EMB_DIM + dcol] = x + (q - x);
        const float df = x - q;
        lsum = fmaf(df, df, lsum);
    }
#pragma unroll
    for (int off = 32; off; off >>= 1) lsum += __shfl_down(lsum, off, 64);
    if ((t & 63) == 0) lred[t >> 6] = lsum;
    __syncthreads();
    if (t == 0) {
        float s = 0.f;
#pragma unroll
        for (int w = 0; w < 8; w++) s += lred[w];
        partial[blockIdx.x] = s;
    }
}

// ---- finish: loss = m + 0.25*m ----
__global__ void vq_finish(const float* __restrict__ partial, float* __restrict__ loss_out) {
    __shared__ float red[256];
    const int t = threadIdx.x;
    float s = 0.f;
    for (int i = t; i < 2048; i += 256) s += partial[i];
    red[t] = s;
    __syncthreads();
    for (int k = 128; k > 0; k >>= 1) {
        if (t < k) red[t] += red[t + k];
        __syncthreads();
    }
    if (t == 0) {
        const float m = red[0] / 8388608.0f;
        loss_out[0] = fmaf(0.25f, m, m);
    }
}

extern "C" void kernel_launch(void* const* d_in, const int* in_sizes, int n_in,
                              void* d_out, int out_size, void* d_ws, size_t ws_size,
                              hipStream_t stream) {
    const float* X = (const float*)d_in[0];      // (32,32,32,256) fp32
    const float* E = (const float*)d_in[1];      // (256,1024) fp32
    float* out = (float*)d_out;

    // workspace layout (bytes)
    char* ws = (char*)d_ws;
    float* ET       = (float*)(ws + 0);            // 1 MB
    float* normE    = (float*)(ws + 1048576);      // 4 KB
    float* partial  = (float*)(ws + 1052672);      // 8 KB
    char*  Es       = ws + 1060864;                // 1 MB
    u64*   gkey     = (u64*)(ws + 2109440);        // 1 MB
    float* gm2      = (float*)(ws + 3158016);      // 512 KB
    u32*   idx_arr  = (u32*)(ws + 3682304);        // 128 KB
    u32*   flaglist = (u32*)(ws + 3813376);        // 128 KB
    u32*   cnt      = (u32*)(ws + 3944448);        // 4 B

    // Xs (bf16 hi/lo, 32 MB) lives in d_out; fully consumed before vq_out overwrites.
    char* Xs = (char*)d_out;

    hipMemsetAsync(cnt, 0, 4, stream);
    vq_transpose<<<64, 256, 0, stream>>>(E, ET);
    vq_norms<<<NUM_EMB / 256, 256, 0, stream>>>(E, normE);
    vq_eprep<<<32, 512, 0, stream>>>(E, Es);
    vq_xprep<<<256, 512, 0, stream>>>(X, Xs);
    vq_gemm<<<1024, 512, 98304, stream>>>(Xs, Es, normE, gkey, gm2);
    vq_combine<<<64, 512, 0, stream>>>(gkey, gm2, idx_arr, flaglist, cnt);
    vq_recheck<<<256, 512, 0, stream>>>(X, E, normE, flaglist, cnt, idx_arr);
    vq_out<<<2048, 512, 0, stream>>>(X, ET, idx_arr, out, partial);
    vq_finish<<<1, 256, 0, stream>>>(partial, out + (out_size - 1));
}

// Round 7
// 135.825 us; speedup vs baseline: 7.1810x; 1.1469x over previous
//
#include <hip/hip_runtime.h>

#define NUM_EMB 1024
#define EMB_DIM 256
#define MARGIN 1e-3f

typedef __attribute__((ext_vector_type(8))) short short8v;
typedef __attribute__((ext_vector_type(4))) float f32x4;
typedef unsigned long long u64;
typedef unsigned int u32;

__device__ __forceinline__ u32 sortable(float f) {
    u32 u = __float_as_uint(f);
    return (u & 0x80000000u) ? ~u : (u | 0x80000000u);
}
__device__ __forceinline__ float unsortable(u32 s) {
    u32 u = (s & 0x80000000u) ? (s & 0x7FFFFFFFu) : ~s;
    return __uint_as_float(u);
}
__device__ __forceinline__ u64 umin64(u64 a, u64 b) { return a < b ? a : b; }

// RNE fp32 -> bf16 bits
__device__ __forceinline__ unsigned short f2bf(float f) {
    u32 u = __float_as_uint(f);
    u32 r = (u + 0x7FFFu + ((u >> 16) & 1u)) >> 16;
    return (unsigned short)r;
}
__device__ __forceinline__ float bf2f(unsigned short h) {
    return __uint_as_float(((u32)h) << 16);
}

#define GLP(p)  ((const __attribute__((address_space(1))) unsigned int*)(p))
#define LDSP(p) ((__attribute__((address_space(3))) unsigned int*)(p))

// ---- fused prep: role-split by blockIdx (logic verbatim from the r4-proven kernels) ----
// bid 0..63   : transpose E -> ET (64x64 tiles)
// bid 64..65  : normE
// bid 66..97  : eprep (Es bf16 hi/lo, swizzled)
// bid 98..353 : xprep (Xs bf16 hi/lo, swizzled)  [Xs aliases d_out]
__global__ __launch_bounds__(512)
void vq_prep(const float* __restrict__ X, const float* __restrict__ E,
             float* __restrict__ ET, float* __restrict__ normE,
             char* __restrict__ Es, char* __restrict__ Xs) {
    __shared__ float tile[64][65];
    const int bid = blockIdx.x;
    const int t = threadIdx.x;
    if (bid < 64) {
        const int j0 = (bid & 15) * 64, d0 = (bid >> 4) * 64;
        const int tj = t & 63, td = t >> 6;
#pragma unroll
        for (int k = 0; k < 8; k++) {
            int dl = k * 8 + td;
            tile[dl][tj] = E[(d0 + dl) * NUM_EMB + j0 + tj];
        }
        __syncthreads();
        const int dd = t & 63, tw = t >> 6;
#pragma unroll
        for (int k = 0; k < 8; k++) {
            int jj = k * 8 + tw;
            ET[(j0 + jj) * EMB_DIM + d0 + dd] = tile[dd][jj];
        }
    } else if (bid < 66) {
        const int j = (bid - 64) * 512 + t;
        float s = 0.f;
#pragma unroll 8
        for (int d = 0; d < EMB_DIM; d++) {
            float v = E[d * NUM_EMB + j];
            s = fmaf(v, v, s);
        }
        normE[j] = s;
    } else if (bid < 98) {
        const int rb = bid - 66;                // 0..31
        const int nblk = rb >> 3, ks = rb & 7;
#pragma unroll
        for (int i = 0; i < 4; i++) {
            int gid = i * 512 + t;              // 256 cols x 8 k8-groups
            int col = gid >> 3;
            int k8 = gid & 7;
            int kg = ks * 64 + k8 * 8;
            int isLo = kg >= 256;
            int d0 = isLo ? kg - 256 : kg;
            int colg = nblk * 256 + col;
            short8v v;
#pragma unroll
            for (int j = 0; j < 8; j++) {
                float e = E[(d0 + j) * NUM_EMB + colg];
                unsigned short h = f2bf(e);
                if (isLo) h = f2bf(e - bf2f(h));
                v[j] = (short)h;
            }
            size_t off = (size_t)nblk * 262144 + (size_t)ks * 32768 +
                         (size_t)(((col * 128 + (k8 * 8) * 2) ^ ((col & 7) << 4)));
            *(short8v*)(Es + off) = v;
        }
    } else {
        const int mblk = bid - 98;              // 0..255
#pragma unroll
        for (int i = 0; i < 8; i++) {
            int gid = i * 512 + t;              // 128 rows x 32 d8-groups
            int row = gid >> 5;
            int d0 = (gid & 31) * 8;
            const float4* xp4 = (const float4*)(X + ((size_t)mblk * 128 + row) * 256 + d0);
            float4 xa = xp4[0], xb = xp4[1];
            float xv[8] = {xa.x, xa.y, xa.z, xa.w, xb.x, xb.y, xb.z, xb.w};
            short8v vh, vl;
#pragma unroll
            for (int j = 0; j < 8; j++) {
                unsigned short h = f2bf(xv[j]);
                vh[j] = (short)h;
                vl[j] = (short)f2bf(xv[j] - bf2f(h));
            }
            int ksh = d0 >> 6, kl = d0 & 63;
            size_t inner = (size_t)(((row * 128 + kl * 2) ^ ((row & 7) << 4)));
            size_t base = (size_t)mblk * 131072;
            *(short8v*)(Xs + base + (size_t)ksh * 16384 + inner) = vh;
            *(short8v*)(Xs + base + (size_t)(ksh + 4) * 16384 + inner) = vl;
        }
    }
}

// ---- GEMM + per-block argmin/second-best (r4-PROVEN data path; 84 VGPR, no spills) ----
// grid 1024 = 256 mblk x 4 nblk; 512 thr; BM=128 BN=256 BK=64; dbuf LDS 96KB
// XCD swizzle: lbid = (bid&7)*128 + (bid>>3)  (bijective; nblk siblings share an XCD L2)
// K=768 schedule: D = Xh*Eh + Xh*El + Xl*Eh
__global__ __launch_bounds__(512, 1)
void vq_gemm(const char* __restrict__ Xs, const char* __restrict__ Es,
             const float* __restrict__ normE,
             u64* __restrict__ gkey, float* __restrict__ gm2) {
    extern __shared__ char smem[];
    const int t = threadIdx.x;
    const int bid = blockIdx.x;
    const int lbid = (bid & 7) * 128 + (bid >> 3);
    const int mblk = lbid >> 2;
    const int nblk = lbid & 3;
    const int w = t >> 6, l = t & 63;
    const int wm = w >> 2, wn = w & 3;
    const int lr = l & 15, lg = l >> 4;
    const int swz = (l & 7) << 4;

    const char* Asrc = Xs + (size_t)mblk * 131072;
    const char* Bsrc = Es + (size_t)nblk * 262144;

    // LDS frag bases (per lane), buf-relative
    const int aB0 = (wm * 64 + lr) * 128 + ((lg * 16) ^ swz);
    const int aB1 = (wm * 64 + lr) * 128 + ((64 + lg * 16) ^ swz);
    const int bB0 = 16384 + (wn * 64 + lr) * 128 + ((lg * 16) ^ swz);
    const int bB1 = 16384 + (wn * 64 + lr) * 128 + ((64 + lg * 16) ^ swz);

    f32x4 acc[4][4];
#pragma unroll
    for (int mt = 0; mt < 4; mt++)
#pragma unroll
        for (int nt = 0; nt < 4; nt++) acc[mt][nt] = (f32x4){0.f, 0.f, 0.f, 0.f};

#define STAGE(aks, bks, buf) {                                                    \
    const char* as_ = Asrc + (aks) * 16384;                                       \
    const char* bs_ = Bsrc + (bks) * 32768;                                       \
    char* ab_ = smem + (buf) * 49152;                                             \
    char* bb_ = ab_ + 16384;                                                      \
    __builtin_amdgcn_global_load_lds(GLP(as_ + t * 16),        LDSP(ab_ + t * 16), 16, 0, 0);        \
    __builtin_amdgcn_global_load_lds(GLP(as_ + 8192 + t * 16), LDSP(ab_ + 8192 + t * 16), 16, 0, 0); \
    __builtin_amdgcn_global_load_lds(GLP(bs_ + t * 16),         LDSP(bb_ + t * 16), 16, 0, 0);        \
    __builtin_amdgcn_global_load_lds(GLP(bs_ + 8192 + t * 16),  LDSP(bb_ + 8192 + t * 16), 16, 0, 0); \
    __builtin_amdgcn_global_load_lds(GLP(bs_ + 16384 + t * 16), LDSP(bb_ + 16384 + t * 16), 16, 0, 0);\
    __builtin_amdgcn_global_load_lds(GLP(bs_ + 24576 + t * 16), LDSP(bb_ + 24576 + t * 16), 16, 0, 0);\
}

    STAGE(0, 0, 0);
#pragma unroll
    for (int s = 0; s < 12; s++) {
        if (s < 11) {
            const int s1 = s + 1;
            const int an = (s1 < 8) ? (s1 & 3) : (s1 - 4);
            const int bn = (s1 < 8) ? s1 : (s1 - 8);
            STAGE(an, bn, s1 & 1);
            asm volatile("s_waitcnt vmcnt(6)" ::: "memory");
        } else {
            asm volatile("s_waitcnt vmcnt(0)" ::: "memory");
        }
        __builtin_amdgcn_s_barrier();
        asm volatile("" ::: "memory");
        {
            const char* s0 = smem + (s & 1) * 49152;
            short8v a0[4], b0[4];
#pragma unroll
            for (int mt = 0; mt < 4; mt++) a0[mt] = *(const short8v*)(s0 + aB0 + mt * 2048);
#pragma unroll
            for (int nt = 0; nt < 4; nt++) b0[nt] = *(const short8v*)(s0 + bB0 + nt * 2048);
#pragma unroll
            for (int mt = 0; mt < 4; mt++)
#pragma unroll
                for (int nt = 0; nt < 4; nt++)
                    acc[mt][nt] = __builtin_amdgcn_mfma_f32_16x16x32_bf16(a0[mt], b0[nt], acc[mt][nt], 0, 0, 0);
            short8v a1[4], b1[4];
#pragma unroll
            for (int mt = 0; mt < 4; mt++) a1[mt] = *(const short8v*)(s0 + aB1 + mt * 2048);
#pragma unroll
            for (int nt = 0; nt < 4; nt++) b1[nt] = *(const short8v*)(s0 + bB1 + nt * 2048);
#pragma unroll
            for (int mt = 0; mt < 4; mt++)
#pragma unroll
                for (int nt = 0; nt < 4; nt++)
                    acc[mt][nt] = __builtin_amdgcn_mfma_f32_16x16x32_bf16(a1[mt], b1[nt], acc[mt][nt], 0, 0, 0);
        }
        asm volatile("" ::: "memory");
        __builtin_amdgcn_s_barrier();
    }
#undef STAGE

    // epilogue: per-lane argmin over nt, then 16-lane reduce; track second-best
    float ne_v[4];
#pragma unroll
    for (int nt = 0; nt < 4; nt++) ne_v[nt] = normE[nblk * 256 + wn * 64 + nt * 16 + lr];

#pragma unroll
    for (int mt = 0; mt < 4; mt++) {
#pragma unroll
        for (int r = 0; r < 4; r++) {
            float m1 = __uint_as_float(0x7F7FFFFFu);   // FLT_MAX
            float m2 = m1;
            u32 col = 0;
#pragma unroll
            for (int nt = 0; nt < 4; nt++) {
                float f = fmaf(-2.0f, acc[mt][nt][r], ne_v[nt]);
                float mx = fmaxf(m1, f);
                m2 = fminf(m2, mx);
                bool p = f < m1;
                m1 = fminf(m1, f);
                u32 cg = (u32)(nblk * 256 + wn * 64 + nt * 16 + lr);
                col = p ? cg : col;
            }
            u64 key = ((u64)sortable(m1) << 32) | col;
#pragma unroll
            for (int off = 1; off < 16; off <<= 1) {
                u64 ko = __shfl_xor(key, off, 16);
                float m1o = __shfl_xor(m1, off, 16);
                float m2o = __shfl_xor(m2, off, 16);
                m2 = fminf(fminf(m2, m2o), fmaxf(m1, m1o));
                m1 = fminf(m1, m1o);
                key = umin64(key, ko);
            }
            if (lr == 0) {
                int slot = (wm * 64 + mt * 16 + lg * 4 + r) * 4 + wn;
                *(u64*)(smem + slot * 16) = key;
                *(float*)(smem + slot * 16 + 8) = m2;
            }
        }
    }
    __syncthreads();
    if (t < 128) {
        u64 k_i[4]; float m2_i[4];
#pragma unroll
        for (int i = 0; i < 4; i++) {
            k_i[i] = *(const u64*)(smem + (t * 4 + i) * 16);
            m2_i[i] = *(const float*)(smem + (t * 4 + i) * 16 + 8);
        }
        u64 K = umin64(umin64(k_i[0], k_i[1]), umin64(k_i[2], k_i[3]));
        float F2 = __uint_as_float(0x7F7FFFFFu);
#pragma unroll
        for (int i = 0; i < 4; i++) {
            float f1i = unsortable((u32)(k_i[i] >> 32));
            F2 = fminf(F2, (k_i[i] == K) ? m2_i[i] : f1i);
        }
        int rowg = mblk * 128 + t;
        gkey[(size_t)nblk * 32768 + rowg] = K;
        gm2[(size_t)nblk * 32768 + rowg] = F2;
    }
}

// ---- combine 4 nblk results -> idx + flag list ----
__global__ __launch_bounds__(512) void vq_combine(const u64* __restrict__ gkey, const float* __restrict__ gm2,
                                                  u32* __restrict__ idx_arr, u32* __restrict__ flaglist,
                                                  u32* __restrict__ cnt) {
    const int row = blockIdx.x * 512 + threadIdx.x;
    u64 k_i[4]; float m2_i[4];
#pragma unroll
    for (int n = 0; n < 4; n++) {
        k_i[n] = gkey[(size_t)n * 32768 + row];
        m2_i[n] = gm2[(size_t)n * 32768 + row];
    }
    u64 K = umin64(umin64(k_i[0], k_i[1]), umin64(k_i[2], k_i[3]));
    float F1 = unsortable((u32)(K >> 32));
    float F2 = __uint_as_float(0x7F7FFFFFu);
#pragma unroll
    for (int n = 0; n < 4; n++) {
        float f1i = unsortable((u32)(k_i[n] >> 32));
        F2 = fminf(F2, (k_i[n] == K) ? m2_i[n] : f1i);
    }
    idx_arr[row] = (u32)(K & 0xFFFFFFFFu);
    if (F2 - F1 < MARGIN) {
        u32 p = atomicAdd(cnt, 1u);
        flaglist[p] = (u32)row;
    }
}

// ---- exact fp32 recheck of flagged rows (bit-identical to verified round-2 math) ----
__global__ __launch_bounds__(512) void vq_recheck(const float* __restrict__ X, const float* __restrict__ E,
                                                  const float* __restrict__ normE,
                                                  const u32* __restrict__ flaglist, const u32* __restrict__ cnt,
                                                  u32* __restrict__ idx_arr) {
    __shared__ float xrow[256];
    __shared__ float r2part[32];
    __shared__ float r2s;
    __shared__ u64 wkey[8];
    const int t = threadIdx.x;
    const int n = (int)*cnt;
    for (int i = blockIdx.x; i < n; i += 256) {
        const int row = (int)flaglist[i];
        __syncthreads();
        if (t < 64) ((float4*)xrow)[t] = ((const float4*)(X + (size_t)row * 256))[t];
        __syncthreads();
        if (t < 32) {
            float s = 0.f;
#pragma unroll
            for (int k = 0; k < 8; k++) {
                float v = xrow[t * 8 + k];
                s = fmaf(v, v, s);
            }
            r2part[t] = s;
        }
        __syncthreads();
        if (t == 0) {
            float s = 0.f;
#pragma unroll
            for (int k = 0; k < 32; k++) s += r2part[k];
            r2s = s;
        }
        __syncthreads();
        const float r2 = r2s;
        const int c0 = t * 2;
        float ax = 0.f, ay = 0.f;
        for (int d = 0; d < 256; d += 4) {
#pragma unroll
            for (int dd = 0; dd < 4; dd++) {
                float xv = xrow[d + dd];
                float2 e = *(const float2*)(E + (d + dd) * NUM_EMB + c0);
                ax = fmaf(xv, e.x, ax);
                ay = fmaf(xv, e.y, ay);
            }
        }
        float2 ne = *(const float2*)(normE + c0);
        float f0 = (r2 + ne.x) - 2.0f * ax;
        float f1 = (r2 + ne.y) - 2.0f * ay;
        u64 k0 = ((u64)sortable(f0) << 32) | (u32)c0;
        u64 k1 = ((u64)sortable(f1) << 32) | (u32)(c0 + 1);
        u64 km = umin64(k0, k1);
#pragma unroll
        for (int off = 32; off; off >>= 1) km = umin64(km, __shfl_xor(km, off, 64));
        if ((t & 63) == 0) wkey[t >> 6] = km;
        __syncthreads();
        if (t == 0) {
            u64 m = wkey[0];
#pragma unroll
            for (int w2 = 1; w2 < 8; w2++) m = umin64(m, wkey[w2]);
            idx_arr[row] = (u32)(m & 0xFFFFFFFFull);
        }
    }
}

// ---- straight-through out + loss partials ----
__global__ __launch_bounds__(512) void vq_out(const float* __restrict__ X, const float* __restrict__ ET,
                                              const u32* __restrict__ idx_arr,
                                              float* __restrict__ out, float* __restrict__ partial) {
    __shared__ float lred[8];
    const int t = threadIdx.x;
    const long long base = (long long)blockIdx.x * 4096;   // 16 rows * 256
    const int dcol = t & 255, half = t >> 8;
    float lsum = 0.f;
#pragma unroll
    for (int rr = 0; rr < 8; rr++) {
        const int r = half * 8 + rr;
        const int row = blockIdx.x * 16 + r;
        const u32 idx = idx_arr[row];
        const float q = ET[(size_t)idx * EMB_DIM + dcol];
        const float x = X[base + r * EMB_DIM + dcol];
        out[base + r * EMB_DIM + dcol] = x + (q - x);
        const float df = x - q;
        lsum = fmaf(df, df, lsum);
    }
#pragma unroll
    for (int off = 32; off; off >>= 1) lsum += __shfl_down(lsum, off, 64);
    if ((t & 63) == 0) lred[t >> 6] = lsum;
    __syncthreads();
    if (t == 0) {
        float s = 0.f;
#pragma unroll
        for (int w = 0; w < 8; w++) s += lred[w];
        partial[blockIdx.x] = s;
    }
}

// ---- finish: loss = m + 0.25*m ----
__global__ void vq_finish(const float* __restrict__ partial, float* __restrict__ loss_out) {
    __shared__ float red[256];
    const int t = threadIdx.x;
    float s = 0.f;
    for (int i = t; i < 2048; i += 256) s += partial[i];
    red[t] = s;
    __syncthreads();
    for (int k = 128; k > 0; k >>= 1) {
        if (t < k) red[t] += red[t + k];
        __syncthreads();
    }
    if (t == 0) {
        const float m = red[0] / 8388608.0f;
        loss_out[0] = fmaf(0.25f, m, m);
    }
}

extern "C" void kernel_launch(void* const* d_in, const int* in_sizes, int n_in,
                              void* d_out, int out_size, void* d_ws, size_t ws_size,
                              hipStream_t stream) {
    const float* X = (const float*)d_in[0];      // (32,32,32,256) fp32
    const float* E = (const float*)d_in[1];      // (256,1024) fp32
    float* out = (float*)d_out;

    // workspace layout (bytes)
    char* ws = (char*)d_ws;
    float* ET       = (float*)(ws + 0);            // 1 MB
    float* normE    = (float*)(ws + 1048576);      // 4 KB
    float* partial  = (float*)(ws + 1052672);      // 8 KB
    char*  Es       = ws + 1060864;                // 1 MB
    u64*   gkey     = (u64*)(ws + 2109440);        // 1 MB
    float* gm2      = (float*)(ws + 3158016);      // 512 KB
    u32*   idx_arr  = (u32*)(ws + 3682304);        // 128 KB
    u32*   flaglist = (u32*)(ws + 3813376);        // 128 KB
    u32*   cnt      = (u32*)(ws + 3944448);        // 4 B

    // Xs (bf16 hi/lo, 32 MB) aliases d_out; fully consumed before vq_out overwrites.
    char* Xs = (char*)d_out;

    hipMemsetAsync(cnt, 0, 4, stream);
    vq_prep<<<354, 512, 0, stream>>>(X, E, ET, normE, Es, Xs);
    vq_gemm<<<1024, 512, 98304, stream>>>(Xs, Es, normE, gkey, gm2);
    vq_combine<<<64, 512, 0, stream>>>(gkey, gm2, idx_arr, flaglist, cnt);
    vq_recheck<<<256, 512, 0, stream>>>(X, E, normE, flaglist, cnt, idx_arr);
    vq_out<<<2048, 512, 0, stream>>>(X, ET, idx_arr, out, partial);
    vq_finish<<<1, 256, 0, stream>>>(partial, out + (out_size - 1));
}

// Round 8
// 135.483 us; speedup vs baseline: 7.1991x; 1.0025x over previous
//
#include <hip/hip_runtime.h>

#define NUM_EMB 1024
#define EMB_DIM 256
#define MARGIN 1e-3f

typedef __attribute__((ext_vector_type(8))) short short8v;
typedef __attribute__((ext_vector_type(4))) float f32x4;
typedef unsigned long long u64;
typedef unsigned int u32;

__device__ __forceinline__ u32 sortable(float f) {
    u32 u = __float_as_uint(f);
    return (u & 0x80000000u) ? ~u : (u | 0x80000000u);
}
__device__ __forceinline__ float unsortable(u32 s) {
    u32 u = (s & 0x80000000u) ? (s & 0x7FFFFFFFu) : ~s;
    return __uint_as_float(u);
}
__device__ __forceinline__ u64 umin64(u64 a, u64 b) { return a < b ? a : b; }

// RNE fp32 -> bf16 bits
__device__ __forceinline__ unsigned short f2bf(float f) {
    u32 u = __float_as_uint(f);
    u32 r = (u + 0x7FFFu + ((u >> 16) & 1u)) >> 16;
    return (unsigned short)r;
}
__device__ __forceinline__ float bf2f(unsigned short h) {
    return __uint_as_float(((u32)h) << 16);
}

#define GLP(p)  ((const __attribute__((address_space(1))) unsigned int*)(p))
#define LDSP(p) ((__attribute__((address_space(3))) unsigned int*)(p))

// ---- fused prep: role-split by blockIdx (r4/r7-proven logic) ----
// bid 0..63   : transpose E -> ET (64x64 tiles)
// bid 64..65  : normE
// bid 66..97  : eprep (Es bf16 hi/lo, swizzled)
// bid 98..353 : xprep (Xs bf16 hi/lo, swizzled)  [Xs aliases d_out]
__global__ __launch_bounds__(512)
void vq_prep(const float* __restrict__ X, const float* __restrict__ E,
             float* __restrict__ ET, float* __restrict__ normE,
             char* __restrict__ Es, char* __restrict__ Xs) {
    __shared__ float tile[64][65];
    const int bid = blockIdx.x;
    const int t = threadIdx.x;
    if (bid < 64) {
        const int j0 = (bid & 15) * 64, d0 = (bid >> 4) * 64;
        const int tj = t & 63, td = t >> 6;
#pragma unroll
        for (int k = 0; k < 8; k++) {
            int dl = k * 8 + td;
            tile[dl][tj] = E[(d0 + dl) * NUM_EMB + j0 + tj];
        }
        __syncthreads();
        const int dd = t & 63, tw = t >> 6;
#pragma unroll
        for (int k = 0; k < 8; k++) {
            int jj = k * 8 + tw;
            ET[(j0 + jj) * EMB_DIM + d0 + dd] = tile[dd][jj];
        }
    } else if (bid < 66) {
        const int j = (bid - 64) * 512 + t;
        float s = 0.f;
#pragma unroll 8
        for (int d = 0; d < EMB_DIM; d++) {
            float v = E[d * NUM_EMB + j];
            s = fmaf(v, v, s);
        }
        normE[j] = s;
    } else if (bid < 98) {
        const int rb = bid - 66;                // 0..31
        const int nblk = rb >> 3, ks = rb & 7;
#pragma unroll
        for (int i = 0; i < 4; i++) {
            int gid = i * 512 + t;              // 256 cols x 8 k8-groups
            int col = gid >> 3;
            int k8 = gid & 7;
            int kg = ks * 64 + k8 * 8;
            int isLo = kg >= 256;
            int d0 = isLo ? kg - 256 : kg;
            int colg = nblk * 256 + col;
            short8v v;
#pragma unroll
            for (int j = 0; j < 8; j++) {
                float e = E[(d0 + j) * NUM_EMB + colg];
                unsigned short h = f2bf(e);
                if (isLo) h = f2bf(e - bf2f(h));
                v[j] = (short)h;
            }
            size_t off = (size_t)nblk * 262144 + (size_t)ks * 32768 +
                         (size_t)(((col * 128 + (k8 * 8) * 2) ^ ((col & 7) << 4)));
            *(short8v*)(Es + off) = v;
        }
    } else {
        const int mblk = bid - 98;              // 0..255
#pragma unroll
        for (int i = 0; i < 8; i++) {
            int gid = i * 512 + t;              // 128 rows x 32 d8-groups
            int row = gid >> 5;
            int d0 = (gid & 31) * 8;
            const float4* xp4 = (const float4*)(X + ((size_t)mblk * 128 + row) * 256 + d0);
            float4 xa = xp4[0], xb = xp4[1];
            float xv[8] = {xa.x, xa.y, xa.z, xa.w, xb.x, xb.y, xb.z, xb.w};
            short8v vh, vl;
#pragma unroll
            for (int j = 0; j < 8; j++) {
                unsigned short h = f2bf(xv[j]);
                vh[j] = (short)h;
                vl[j] = (short)f2bf(xv[j] - bf2f(h));
            }
            int ksh = d0 >> 6, kl = d0 & 63;
            size_t inner = (size_t)(((row * 128 + kl * 2) ^ ((row & 7) << 4)));
            size_t base = (size_t)mblk * 131072;
            *(short8v*)(Xs + base + (size_t)ksh * 16384 + inner) = vh;
            *(short8v*)(Xs + base + (size_t)(ksh + 4) * 16384 + inner) = vl;
        }
    }
}

// ---- GEMM + per-block argmin/second-best ----
// grid 1024 = 256 mblk x 4 nblk; 512 thr; BM=128 BN=256 BK=64
// LDS 80KB -> 2 blocks/CU: B dbuf 2x32K @0, A single-buf 16K @65536
// (A restaged every step; barrier2 separates compute(s) from STAGE_A(s+1))
// FIFO: prologue A0+B0 (6); step: +B(s+1)(4), vmcnt(4) drains A(s)+B(s); last vmcnt(0)
// XCD swizzle: lbid = (bid&7)*128 + (bid>>3)
// K=768 schedule: D = Xh*Eh + Xh*El + Xl*Eh
__global__ __launch_bounds__(512, 4)
void vq_gemm(const char* __restrict__ Xs, const char* __restrict__ Es,
             const float* __restrict__ normE,
             u64* __restrict__ gkey, float* __restrict__ gm2) {
    extern __shared__ char smem[];
    const int t = threadIdx.x;
    const int bid = blockIdx.x;
    const int lbid = (bid & 7) * 128 + (bid >> 3);
    const int mblk = lbid >> 2;
    const int nblk = lbid & 3;
    const int w = t >> 6, l = t & 63;
    const int wm = w >> 2, wn = w & 3;
    const int lr = l & 15, lg = l >> 4;
    const int swz = (l & 7) << 4;

    const char* Asrc = Xs + (size_t)mblk * 131072;
    const char* Bsrc = Es + (size_t)nblk * 262144;

    // LDS frag bases (per lane)
    const int aB0 = 65536 + (wm * 64 + lr) * 128 + ((lg * 16) ^ swz);
    const int aB1 = 65536 + (wm * 64 + lr) * 128 + ((64 + lg * 16) ^ swz);
    const int bB0 = (wn * 64 + lr) * 128 + ((lg * 16) ^ swz);
    const int bB1 = (wn * 64 + lr) * 128 + ((64 + lg * 16) ^ swz);

    f32x4 acc[4][4];
#pragma unroll
    for (int mt = 0; mt < 4; mt++)
#pragma unroll
        for (int nt = 0; nt < 4; nt++) acc[mt][nt] = (f32x4){0.f, 0.f, 0.f, 0.f};

#define STAGE_A(aks) {                                                            \
    const char* as_ = Asrc + (aks) * 16384;                                       \
    __builtin_amdgcn_global_load_lds(GLP(as_ + t * 16),        LDSP(smem + 65536 + t * 16), 16, 0, 0);        \
    __builtin_amdgcn_global_load_lds(GLP(as_ + 8192 + t * 16), LDSP(smem + 65536 + 8192 + t * 16), 16, 0, 0); \
}
#define STAGE_B(bks, buf) {                                                       \
    const char* bs_ = Bsrc + (bks) * 32768;                                       \
    char* bb_ = smem + (buf) * 32768;                                             \
    __builtin_amdgcn_global_load_lds(GLP(bs_ + t * 16),         LDSP(bb_ + t * 16), 16, 0, 0);        \
    __builtin_amdgcn_global_load_lds(GLP(bs_ + 8192 + t * 16),  LDSP(bb_ + 8192 + t * 16), 16, 0, 0); \
    __builtin_amdgcn_global_load_lds(GLP(bs_ + 16384 + t * 16), LDSP(bb_ + 16384 + t * 16), 16, 0, 0);\
    __builtin_amdgcn_global_load_lds(GLP(bs_ + 24576 + t * 16), LDSP(bb_ + 24576 + t * 16), 16, 0, 0);\
}

    STAGE_A(0);
    STAGE_B(0, 0);
#pragma unroll
    for (int s = 0; s < 12; s++) {
        if (s < 11) {
            const int s1 = s + 1;
            const int bn = (s1 < 8) ? s1 : (s1 - 8);
            STAGE_B(bn, s1 & 1);
            asm volatile("s_waitcnt vmcnt(4)" ::: "memory");
        } else {
            asm volatile("s_waitcnt vmcnt(0)" ::: "memory");
        }
        __builtin_amdgcn_s_barrier();
        asm volatile("" ::: "memory");
        {
            const int bT = (s & 1) * 32768;
            short8v a0[4], b0[4];
#pragma unroll
            for (int mt = 0; mt < 4; mt++) a0[mt] = *(const short8v*)(smem + aB0 + mt * 2048);
#pragma unroll
            for (int nt = 0; nt < 4; nt++) b0[nt] = *(const short8v*)(smem + bT + bB0 + nt * 2048);
#pragma unroll
            for (int mt = 0; mt < 4; mt++)
#pragma unroll
                for (int nt = 0; nt < 4; nt++)
                    acc[mt][nt] = __builtin_amdgcn_mfma_f32_16x16x32_bf16(a0[mt], b0[nt], acc[mt][nt], 0, 0, 0);
            short8v a1[4], b1[4];
#pragma unroll
            for (int mt = 0; mt < 4; mt++) a1[mt] = *(const short8v*)(smem + aB1 + mt * 2048);
#pragma unroll
            for (int nt = 0; nt < 4; nt++) b1[nt] = *(const short8v*)(smem + bT + bB1 + nt * 2048);
#pragma unroll
            for (int mt = 0; mt < 4; mt++)
#pragma unroll
                for (int nt = 0; nt < 4; nt++)
                    acc[mt][nt] = __builtin_amdgcn_mfma_f32_16x16x32_bf16(a1[mt], b1[nt], acc[mt][nt], 0, 0, 0);
        }
        asm volatile("" ::: "memory");
        __builtin_amdgcn_s_barrier();
        if (s < 11) {
            const int s1 = s + 1;
            const int an = (s1 < 8) ? (s1 & 3) : (s1 - 4);
            STAGE_A(an);
        }
    }
#undef STAGE_A
#undef STAGE_B

    // epilogue: per-lane argmin over nt, then 16-lane reduce; track second-best
    float ne_v[4];
#pragma unroll
    for (int nt = 0; nt < 4; nt++) ne_v[nt] = normE[nblk * 256 + wn * 64 + nt * 16 + lr];

#pragma unroll
    for (int mt = 0; mt < 4; mt++) {
#pragma unroll
        for (int r = 0; r < 4; r++) {
            float m1 = __uint_as_float(0x7F7FFFFFu);   // FLT_MAX
            float m2 = m1;
            u32 col = 0;
#pragma unroll
            for (int nt = 0; nt < 4; nt++) {
                float f = fmaf(-2.0f, acc[mt][nt][r], ne_v[nt]);
                float mx = fmaxf(m1, f);
                m2 = fminf(m2, mx);
                bool p = f < m1;
                m1 = fminf(m1, f);
                u32 cg = (u32)(nblk * 256 + wn * 64 + nt * 16 + lr);
                col = p ? cg : col;
            }
            u64 key = ((u64)sortable(m1) << 32) | col;
#pragma unroll
            for (int off = 1; off < 16; off <<= 1) {
                u64 ko = __shfl_xor(key, off, 16);
                float m1o = __shfl_xor(m1, off, 16);
                float m2o = __shfl_xor(m2, off, 16);
                m2 = fminf(fminf(m2, m2o), fmaxf(m1, m1o));
                m1 = fminf(m1, m1o);
                key = umin64(key, ko);
            }
            if (lr == 0) {
                int slot = (wm * 64 + mt * 16 + lg * 4 + r) * 4 + wn;
                *(u64*)(smem + slot * 16) = key;
                *(float*)(smem + slot * 16 + 8) = m2;
            }
        }
    }
    __syncthreads();
    if (t < 128) {
        u64 k_i[4]; float m2_i[4];
#pragma unroll
        for (int i = 0; i < 4; i++) {
            k_i[i] = *(const u64*)(smem + (t * 4 + i) * 16);
            m2_i[i] = *(const float*)(smem + (t * 4 + i) * 16 + 8);
        }
        u64 K = umin64(umin64(k_i[0], k_i[1]), umin64(k_i[2], k_i[3]));
        float F2 = __uint_as_float(0x7F7FFFFFu);
#pragma unroll
        for (int i = 0; i < 4; i++) {
            float f1i = unsortable((u32)(k_i[i] >> 32));
            F2 = fminf(F2, (k_i[i] == K) ? m2_i[i] : f1i);
        }
        int rowg = mblk * 128 + t;
        gkey[(size_t)nblk * 32768 + rowg] = K;
        gm2[(size_t)nblk * 32768 + rowg] = F2;
    }
}

// ---- combine 4 nblk results -> idx + flag list ----
__global__ __launch_bounds__(512) void vq_combine(const u64* __restrict__ gkey, const float* __restrict__ gm2,
                                                  u32* __restrict__ idx_arr, u32* __restrict__ flaglist,
                                                  u32* __restrict__ cnt) {
    const int row = blockIdx.x * 512 + threadIdx.x;
    u64 k_i[4]; float m2_i[4];
#pragma unroll
    for (int n = 0; n < 4; n++) {
        k_i[n] = gkey[(size_t)n * 32768 + row];
        m2_i[n] = gm2[(size_t)n * 32768 + row];
    }
    u64 K = umin64(umin64(k_i[0], k_i[1]), umin64(k_i[2], k_i[3]));
    float F1 = unsortable((u32)(K >> 32));
    float F2 = __uint_as_float(0x7F7FFFFFu);
#pragma unroll
    for (int n = 0; n < 4; n++) {
        float f1i = unsortable((u32)(k_i[n] >> 32));
        F2 = fminf(F2, (k_i[n] == K) ? m2_i[n] : f1i);
    }
    idx_arr[row] = (u32)(K & 0xFFFFFFFFu);
    if (F2 - F1 < MARGIN) {
        u32 p = atomicAdd(cnt, 1u);
        flaglist[p] = (u32)row;
    }
}

// ---- exact fp32 recheck of flagged rows (bit-identical to verified round-2 math) ----
__global__ __launch_bounds__(512) void vq_recheck(const float* __restrict__ X, const float* __restrict__ E,
                                                  const float* __restrict__ normE,
                                                  const u32* __restrict__ flaglist, const u32* __restrict__ cnt,
                                                  u32* __restrict__ idx_arr) {
    __shared__ float xrow[256];
    __shared__ float r2part[32];
    __shared__ float r2s;
    __shared__ u64 wkey[8];
    const int t = threadIdx.x;
    const int n = (int)*cnt;
    for (int i = blockIdx.x; i < n; i += 256) {
        const int row = (int)flaglist[i];
        __syncthreads();
        if (t < 64) ((float4*)xrow)[t] = ((const float4*)(X + (size_t)row * 256))[t];
        __syncthreads();
        if (t < 32) {
            float s = 0.f;
#pragma unroll
            for (int k = 0; k < 8; k++) {
                float v = xrow[t * 8 + k];
                s = fmaf(v, v, s);
            }
            r2part[t] = s;
        }
        __syncthreads();
        if (t == 0) {
            float s = 0.f;
#pragma unroll
            for (int k = 0; k < 32; k++) s += r2part[k];
            r2s = s;
        }
        __syncthreads();
        const float r2 = r2s;
        const int c0 = t * 2;
        float ax = 0.f, ay = 0.f;
        for (int d = 0; d < 256; d += 4) {
#pragma unroll
            for (int dd = 0; dd < 4; dd++) {
                float xv = xrow[d + dd];
                float2 e = *(const float2*)(E + (d + dd) * NUM_EMB + c0);
                ax = fmaf(xv, e.x, ax);
                ay = fmaf(xv, e.y, ay);
            }
        }
        float2 ne = *(const float2*)(normE + c0);
        float f0 = (r2 + ne.x) - 2.0f * ax;
        float f1 = (r2 + ne.y) - 2.0f * ay;
        u64 k0 = ((u64)sortable(f0) << 32) | (u32)c0;
        u64 k1 = ((u64)sortable(f1) << 32) | (u32)(c0 + 1);
        u64 km = umin64(k0, k1);
#pragma unroll
        for (int off = 32; off; off >>= 1) km = umin64(km, __shfl_xor(km, off, 64));
        if ((t & 63) == 0) wkey[t >> 6] = km;
        __syncthreads();
        if (t == 0) {
            u64 m = wkey[0];
#pragma unroll
            for (int w2 = 1; w2 < 8; w2++) m = umin64(m, wkey[w2]);
            idx_arr[row] = (u32)(m & 0xFFFFFFFFull);
        }
    }
}

// ---- straight-through out + loss partials ----
__global__ __launch_bounds__(512) void vq_out(const float* __restrict__ X, const float* __restrict__ ET,
                                              const u32* __restrict__ idx_arr,
                                              float* __restrict__ out, float* __restrict__ partial) {
    __shared__ float lred[8];
    const int t = threadIdx.x;
    const long long base = (long long)blockIdx.x * 4096;   // 16 rows * 256
    const int dcol = t & 255, half = t >> 8;
    float lsum = 0.f;
#pragma unroll
    for (int rr = 0; rr < 8; rr++) {
        const int r = half * 8 + rr;
        const int row = blockIdx.x * 16 + r;
        const u32 idx = idx_arr[row];
        const float q = ET[(size_t)idx * EMB_DIM + dcol];
        const float x = X[base + r * EMB_DIM + dcol];
        out[base + r * EMB_DIM + dcol] = x + (q - x);
        const float df = x - q;
        lsum = fmaf(df, df, lsum);
    }
#pragma unroll
    for (int off = 32; off; off >>= 1) lsum += __shfl_down(lsum, off, 64);
    if ((t & 63) == 0) lred[t >> 6] = lsum;
    __syncthreads();
    if (t == 0) {
        float s = 0.f;
#pragma unroll
        for (int w = 0; w < 8; w++) s += lred[w];
        partial[blockIdx.x] = s;
    }
}

// ---- finish: loss = m + 0.25*m ----
__global__ void vq_finish(const float* __restrict__ partial, float* __restrict__ loss_out) {
    __shared__ float red[256];
    const int t = threadIdx.x;
    float s = 0.f;
    for (int i = t; i < 2048; i += 256) s += partial[i];
    red[t] = s;
    __syncthreads();
    for (int k = 128; k > 0; k >>= 1) {
        if (t < k) red[t] += red[t + k];
        __syncthreads();
    }
    if (t == 0) {
        const float m = red[0] / 8388608.0f;
        loss_out[0] = fmaf(0.25f, m, m);
    }
}

extern "C" void kernel_launch(void* const* d_in, const int* in_sizes, int n_in,
                              void* d_out, int out_size, void* d_ws, size_t ws_size,
                              hipStream_t stream) {
    const float* X = (const float*)d_in[0];      // (32,32,32,256) fp32
    const float* E = (const float*)d_in[1];      // (256,1024) fp32
    float* out = (float*)d_out;

    // workspace layout (bytes)
    char* ws = (char*)d_ws;
    float* ET       = (float*)(ws + 0);            // 1 MB
    float* normE    = (float*)(ws + 1048576);      // 4 KB
    float* partial  = (float*)(ws + 1052672);      // 8 KB
    char*  Es       = ws + 1060864;                // 1 MB
    u64*   gkey     = (u64*)(ws + 2109440);        // 1 MB
    float* gm2      = (float*)(ws + 3158016);      // 512 KB
    u32*   idx_arr  = (u32*)(ws + 3682304);        // 128 KB
    u32*   flaglist = (u32*)(ws + 3813376);        // 128 KB
    u32*   cnt      = (u32*)(ws + 3944448);        // 4 B

    // Xs (bf16 hi/lo, 32 MB) aliases d_out; fully consumed before vq_out overwrites.
    char* Xs = (char*)d_out;

    hipMemsetAsync(cnt, 0, 4, stream);
    vq_prep<<<354, 512, 0, stream>>>(X, E, ET, normE, Es, Xs);
    vq_gemm<<<1024, 512, 81920, stream>>>(Xs, Es, normE, gkey, gm2);
    vq_combine<<<64, 512, 0, stream>>>(gkey, gm2, idx_arr, flaglist, cnt);
    vq_recheck<<<256, 512, 0, stream>>>(X, E, normE, flaglist, cnt, idx_arr);
    vq_out<<<2048, 512, 0, stream>>>(X, ET, idx_arr, out, partial);
    vq_finish<<<1, 256, 0, stream>>>(partial, out + (out_size - 1));
}